// Round 3
// baseline (182.704 us; speedup 1.0000x reference)
//
#include <hip/hip_runtime.h>
#include <hip/hip_fp16.h>
#include <hip/hip_bf16.h>
#include <stdint.h>

#define IN_F 8192
#define OUT_F 8192
#define NGROUPS 64
#define QW_COLS 1024   // IN_F / 8 packed int32 per output row
#define QZ_COLS 8      // ceil(64/8)
#define M_TOTAL 128    // 4*32
#define BN 32
#define BK 128         // == GROUP_SIZE: one (scale, zero) per col per tile
#define NITER (IN_F / BK)  // 64

typedef _Float16 half8 __attribute__((ext_vector_type(8)));
typedef float floatx4 __attribute__((ext_vector_type(4)));

#define LSTRIDE 136  // 128 + 8 pad (272 B rows -> 2-way bank alias: free)

// exact dequant: q*s and z*s have <=16-bit mantissas; fma rounds once in f32,
// then one rounding to f16 == reference's f32-compute -> f16 cast.
__device__ inline uint16_t dq16(uint32_t q, float sf, float nzs) {
  float fw = fmaf((float)q, sf, nzs);
  __half h = __float2half(fw);
  return __builtin_bit_cast(uint16_t, h);
}

// MODE 0: x/scales are f32 (harness upcast of jnp.float16), out is f32.
// MODE 1: x/scales are native f16, out is bf16.
template <int MODE>
__device__ void run(uint16_t* xs, uint16_t* wsl, const void* xp,
                    const int* __restrict__ qweight, const void* sp,
                    const int* __restrict__ qzeros,
                    const float* __restrict__ bias, void* outp) {
  const int tid = threadIdx.x;
  const int n0 = blockIdx.x * BN;

  const int wave = tid >> 6;
  const int lane = tid & 63;
  const int ni = wave & 1;    // 16-col strip within the 32-wide N tile
  const int mgrp = wave >> 1; // 32-row group of M (4 groups)
  const int quad = lane >> 4;
  const int l15 = lane & 15;

  floatx4 acc[2] = {};

  // weight staging map: 32 cols x 16 packed words = 512 threads, 1 word each
  const int wcol = tid >> 4;
  const int wwp = tid & 15;
  const long long qw_row = (long long)(n0 + wcol) * QW_COLS;

  for (int it = 0; it < NITER; ++it) {
    const int k0 = it * BK;

    // ---- stage x tile: 128 rows x 128 k -> f16 LDS
    if (MODE == 0) {
      const float* x = (const float*)xp;
#pragma unroll
      for (int r = 0; r < 8; ++r) {
        int c = tid + 512 * r;          // 4096 chunks of 4 floats
        int row = c >> 5;
        int c4 = (c & 31) * 4;
        float4 v = *(const float4*)(x + (long long)row * IN_F + k0 + c4);
        uint16_t* d = &xs[row * LSTRIDE + c4];
        d[0] = __builtin_bit_cast(uint16_t, __float2half(v.x));
        d[1] = __builtin_bit_cast(uint16_t, __float2half(v.y));
        d[2] = __builtin_bit_cast(uint16_t, __float2half(v.z));
        d[3] = __builtin_bit_cast(uint16_t, __float2half(v.w));
      }
    } else {
      const uint16_t* x = (const uint16_t*)xp;
#pragma unroll
      for (int r = 0; r < 4; ++r) {
        int c = tid + 512 * r;          // 2048 chunks of 8 halves
        int row = c >> 4;
        int c8 = (c & 15) * 8;
        uint4 v = *(const uint4*)(x + (long long)row * IN_F + k0 + c8);
        *(uint4*)(&xs[row * LSTRIDE + c8]) = v;
      }
    }

    // ---- dequant + stage weight tile: 32 cols x 128 k (one group)
    {
      const int g = k0 >> 7;
      float sf;
      if (MODE == 0) {
        sf = ((const float*)sp)[(long long)(n0 + wcol) * NGROUPS + g];
      } else {
        uint16_t sb = ((const uint16_t*)sp)[(long long)(n0 + wcol) * NGROUPS + g];
        sf = __half2float(__builtin_bit_cast(__half, sb));
      }
      const int zw = qzeros[(long long)(n0 + wcol) * QZ_COLS + (g >> 3)];
      const float zf = (float)((uint32_t)(zw >> ((g & 7) * 4)) & 0xFu);
      const float nzs = -zf * sf;

      const uint32_t w0 = (uint32_t)qweight[qw_row + (k0 >> 3) + wwp];
      union { uint16_t h[8]; uint4 v; } r;
#pragma unroll
      for (int j = 0; j < 8; ++j) r.h[j] = dq16((w0 >> (4 * j)) & 15u, sf, nzs);
      *(uint4*)(&wsl[wcol * LSTRIDE + wwp * 8]) = r.v;
    }

    __syncthreads();

    // ---- MFMA: 4 K32 steps; wave does 2 M-subtiles x 1 N-strip
#pragma unroll
    for (int kk = 0; kk < 4; ++kk) {
      const int ko = kk * 32 + quad * 8;
      half8 b = *(const half8*)(&wsl[(ni * 16 + l15) * LSTRIDE + ko]);
#pragma unroll
      for (int sm = 0; sm < 2; ++sm) {
        half8 a = *(const half8*)(&xs[(mgrp * 32 + sm * 16 + l15) * LSTRIDE + ko]);
        acc[sm] = __builtin_amdgcn_mfma_f32_16x16x32_f16(a, b, acc[sm], 0, 0, 0);
      }
    }

    __syncthreads();
  }

  // ---- epilogue: add bias, store in output dtype (block owns full K)
  const int n = n0 + ni * 16 + l15;
  const float bv = bias[n];
#pragma unroll
  for (int sm = 0; sm < 2; ++sm) {
#pragma unroll
    for (int i = 0; i < 4; ++i) {
      int m = mgrp * 32 + sm * 16 + quad * 4 + i;  // C/D: row=quad*4+reg, col=l15
      float val = acc[sm][i] + bv;
      if (MODE == 0) {
        ((float*)outp)[(long long)m * OUT_F + n] = val;
      } else {
        __hip_bfloat16 o = __float2bfloat16(val);
        ((uint16_t*)outp)[(long long)m * OUT_F + n] = __builtin_bit_cast(uint16_t, o);
      }
    }
  }
}

__global__ __launch_bounds__(512) void awq_main(
    const void* __restrict__ x, const int* __restrict__ qweight,
    const void* __restrict__ scales, const int* __restrict__ qzeros,
    const float* __restrict__ bias, void* __restrict__ out) {
  __shared__ uint16_t xs[M_TOTAL * LSTRIDE];  // 34816 B
  __shared__ uint16_t wsl[BN * LSTRIDE];      // 8704 B
  // dtype sniff on scales word 0 (values in [0.001, 0.02], sign 0):
  //   f32: bits[30:23] = biased exp in [117,122]  -> field in [100,130]
  //   f16 pair: bits[31:23] = high-half bits[15:7] in [40,74]
  const uint32_t w = *(const uint32_t*)scales;
  const uint32_t e = (w >> 23) & 0xFFu;
  if (e >= 100u && e <= 130u)
    run<0>(xs, wsl, x, qweight, scales, qzeros, bias, out);
  else
    run<1>(xs, wsl, x, qweight, scales, qzeros, bias, out);
}

extern "C" void kernel_launch(void* const* d_in, const int* in_sizes, int n_in,
                              void* d_out, int out_size, void* d_ws, size_t ws_size,
                              hipStream_t stream) {
  awq_main<<<OUT_F / BN, 512, 0, stream>>>(
      d_in[0], (const int*)d_in[1], d_in[2], (const int*)d_in[3],
      (const float*)d_in[4], d_out);
}

// Round 4
// 129.123 us; speedup vs baseline: 1.4150x; 1.4150x over previous
//
#include <hip/hip_runtime.h>
#include <hip/hip_fp16.h>
#include <stdint.h>

#define IN_F 8192
#define OUT_F 8192
#define NGROUPS 64
#define QW_COLS 1024   // IN_F/8 packed int32 per output row
#define QZ_COLS 8
#define M_TOTAL 128
#define BN 64
#define BK 128         // == GROUP_SIZE: one (scale, zero) per col per tile
#define KSPLIT 4
#define KRANGE (IN_F / KSPLIT)  // 2048
#define NITER (KRANGE / BK)     // 16

typedef _Float16 half8 __attribute__((ext_vector_type(8)));
typedef float floatx4 __attribute__((ext_vector_type(4)));

#define LSTRIDE 136  // 128 + 8 pad halves; 68-dword row stride -> 2-way alias (free)

// exact dequant: fma rounds once in f32, then once to f16 == reference.
__device__ inline uint16_t dq16(uint32_t q, float sf, float nzs) {
  float fw = fmaf((float)q, sf, nzs);
  __half h = __float2half(fw);
  return __builtin_bit_cast(uint16_t, h);
}

// XF16 = 1: x staged from pre-converted f16 in ws. XF16 = 0: direct f32 reads.
template <int XF16>
__global__ __launch_bounds__(512) void awq_main(
    const float* __restrict__ xf32, const uint16_t* __restrict__ xf16,
    const int* __restrict__ qweight, const float* __restrict__ scales,
    const int* __restrict__ qzeros, float* __restrict__ out) {
  __shared__ uint16_t xs[M_TOTAL * LSTRIDE];  // 34816 B
  __shared__ uint16_t wsl[BN * LSTRIDE];      // 17408 B

  const int tid = threadIdx.x;
  const int bx = blockIdx.x;
  const int ntile = bx & 127;
  const int kslice = bx >> 7;
  const int n0 = ntile * BN;
  const int kbase = kslice * KRANGE;

  const int wave = tid >> 6;
  const int lane = tid & 63;
  const int ni = wave & 3;    // 16-col strip of the 64-wide N tile
  const int mgrp = wave >> 2; // 64-row half of M
  const int quad = lane >> 4;
  const int l15 = lane & 15;

  floatx4 acc[4] = {};

  // weight staging: 64 cols x 8 word-pairs = 512 threads
  const int wcol = tid >> 3;
  const int wwp = tid & 7;
  const long long qw_row = (long long)(n0 + wcol) * QW_COLS;

  for (int it = 0; it < NITER; ++it) {
    const int k0 = kbase + it * BK;

    // ---- stage x tile: 128 rows x 128 k (f16) = 2048 16B chunks, 4/thread
    if (XF16) {
#pragma unroll
      for (int r = 0; r < 4; ++r) {
        int c = tid + 512 * r;
        int row = c >> 4;
        int c8 = (c & 15) * 8;
        uint4 v = *(const uint4*)(xf16 + (long long)row * IN_F + k0 + c8);
        *(uint4*)(&xs[row * LSTRIDE + c8]) = v;
      }
    } else {
#pragma unroll
      for (int r = 0; r < 8; ++r) {
        int c = tid + 512 * r;
        int row = c >> 5;
        int c4 = (c & 31) * 4;
        float4 v = *(const float4*)(xf32 + (long long)row * IN_F + k0 + c4);
        uint16_t* d = &xs[row * LSTRIDE + c4];
        d[0] = __builtin_bit_cast(uint16_t, __float2half(v.x));
        d[1] = __builtin_bit_cast(uint16_t, __float2half(v.y));
        d[2] = __builtin_bit_cast(uint16_t, __float2half(v.z));
        d[3] = __builtin_bit_cast(uint16_t, __float2half(v.w));
      }
    }

    // ---- dequant + stage weight tile: 64 cols x 128 k (one group)
    {
      const int g = k0 >> 7;
      const float sf = scales[(long long)(n0 + wcol) * NGROUPS + g];
      const int zw = qzeros[(long long)(n0 + wcol) * QZ_COLS + (g >> 3)];
      const float zf = (float)((uint32_t)(zw >> ((g & 7) * 4)) & 0xFu);
      const float nzs = -zf * sf;

      const long long qi = qw_row + (k0 >> 3) + wwp * 2;
      const uint32_t w0 = (uint32_t)qweight[qi];
      const uint32_t w1 = (uint32_t)qweight[qi + 1];
      union { uint16_t h[16]; uint4 v[2]; } r;
#pragma unroll
      for (int j = 0; j < 8; ++j) r.h[j] = dq16((w0 >> (4 * j)) & 15u, sf, nzs);
#pragma unroll
      for (int j = 0; j < 8; ++j) r.h[8 + j] = dq16((w1 >> (4 * j)) & 15u, sf, nzs);
      uint4* dst = (uint4*)(&wsl[wcol * LSTRIDE + wwp * 16]);
      dst[0] = r.v[0];
      dst[1] = r.v[1];
    }

    __syncthreads();

    // ---- MFMA: 4 K32 steps; wave does 4 M-subtiles x 1 N-strip
#pragma unroll
    for (int kk = 0; kk < 4; ++kk) {
      const int ko = kk * 32 + quad * 8;
      half8 b = *(const half8*)(&wsl[(ni * 16 + l15) * LSTRIDE + ko]);
#pragma unroll
      for (int sm = 0; sm < 4; ++sm) {
        half8 a = *(const half8*)(&xs[(mgrp * 64 + sm * 16 + l15) * LSTRIDE + ko]);
        acc[sm] = __builtin_amdgcn_mfma_f32_16x16x32_f16(a, b, acc[sm], 0, 0, 0);
      }
    }

    __syncthreads();
  }

  // ---- epilogue: accumulate K-split partials (out pre-set to bias)
  const int n = n0 + ni * 16 + l15;
#pragma unroll
  for (int sm = 0; sm < 4; ++sm) {
#pragma unroll
    for (int i = 0; i < 4; ++i) {
      int m = mgrp * 64 + sm * 16 + quad * 4 + i;  // C/D: row=quad*4+reg, col=l15
      atomicAdd(out + (long long)m * OUT_F + n, acc[sm][i]);
    }
  }
}

// fused prologue: out = bias (broadcast rows) and ws = f16(x). 1M elems each.
__global__ __launch_bounds__(256) void prologue(
    const float* __restrict__ x, const float* __restrict__ bias,
    float* __restrict__ out, uint16_t* __restrict__ xf16) {
  int idx = (blockIdx.x * 256 + threadIdx.x) * 8;
  // bias init (f32 x2 float4)
  float4 b0 = *(const float4*)(bias + (idx & (OUT_F - 1)));
  float4 b1 = *(const float4*)(bias + ((idx + 4) & (OUT_F - 1)));
  *(float4*)(out + idx) = b0;
  *(float4*)(out + idx + 4) = b1;
  // x convert
  float4 v0 = *(const float4*)(x + idx);
  float4 v1 = *(const float4*)(x + idx + 4);
  union { uint16_t h[8]; uint4 v; } r;
  r.h[0] = __builtin_bit_cast(uint16_t, __float2half(v0.x));
  r.h[1] = __builtin_bit_cast(uint16_t, __float2half(v0.y));
  r.h[2] = __builtin_bit_cast(uint16_t, __float2half(v0.z));
  r.h[3] = __builtin_bit_cast(uint16_t, __float2half(v0.w));
  r.h[4] = __builtin_bit_cast(uint16_t, __float2half(v1.x));
  r.h[5] = __builtin_bit_cast(uint16_t, __float2half(v1.y));
  r.h[6] = __builtin_bit_cast(uint16_t, __float2half(v1.z));
  r.h[7] = __builtin_bit_cast(uint16_t, __float2half(v1.w));
  *(uint4*)(xf16 + idx) = r.v;
}

__global__ __launch_bounds__(256) void init_out(const float* __restrict__ bias,
                                                float* __restrict__ out) {
  int idx = (blockIdx.x * 256 + threadIdx.x) * 4;
  float4 b = *(const float4*)(bias + (idx & (OUT_F - 1)));
  *(float4*)(out + idx) = b;
}

extern "C" void kernel_launch(void* const* d_in, const int* in_sizes, int n_in,
                              void* d_out, int out_size, void* d_ws, size_t ws_size,
                              hipStream_t stream) {
  const float* x = (const float*)d_in[0];
  const int* qw = (const int*)d_in[1];
  const float* sc = (const float*)d_in[2];
  const int* qz = (const int*)d_in[3];
  const float* bias = (const float*)d_in[4];
  float* out = (float*)d_out;
  uint16_t* xf16 = (uint16_t*)d_ws;

  const size_t need = (size_t)M_TOTAL * IN_F * sizeof(uint16_t);  // 2 MiB
  if (ws_size >= need) {
    prologue<<<(M_TOTAL * OUT_F) / (256 * 8), 256, 0, stream>>>(x, bias, out, xf16);
    awq_main<1><<<128 * KSPLIT, 512, 0, stream>>>(x, xf16, qw, sc, qz, out);
  } else {
    init_out<<<(M_TOTAL * OUT_F) / (256 * 4), 256, 0, stream>>>(bias, out);
    awq_main<0><<<128 * KSPLIT, 512, 0, stream>>>(x, xf16, qw, sc, qz, out);
  }
}